// Round 7
// baseline (210.445 us; speedup 1.0000x reference)
//
#include <hip/hip_runtime.h>
#include <hip/hip_bf16.h>

#define N_NODES 100000
#define N_EDGES 1200000
#define D_IN 256
#define D_OUT 64
#define N_TILES (N_NODES / 16)                     // 6250 row tiles of 16

// fused kernel striping: period 4 = 1 GEMM block (16 tiles) + 3 edge blocks
#define TILES_PER_BLOCK 16                         // 4 waves x 4 tiles
#define GEMM_NB ((N_TILES + TILES_PER_BLOCK - 1) / TILES_PER_BLOCK) // 391
#define EDGE4_NB ((N_EDGES / 4 + 255) / 256)       // 1172 (4 edges/thread)
#define FUSED_NB (GEMM_NB * 4)                     // 1564 (391*3=1173 edge slots)

#define FILL_PASSES 2
#define PASS_NODES (N_NODES / FILL_PASSES)         // 50000
#define FILL_NB EDGE4_NB

#define SCAN_BLOCK 1024
#define SCAN_NB ((N_NODES + SCAN_BLOCK - 1) / SCAN_BLOCK) // 98

typedef __bf16 bf16_t;
typedef bf16_t bf16x8 __attribute__((ext_vector_type(8)));
typedef float f32x4 __attribute__((ext_vector_type(4)));

// pack (col, val) into 4B: col<<15 | round(val*32767). val in [0,1).
__device__ __forceinline__ unsigned pack_cv(int col, float val) {
    return ((unsigned)col << 15) | (unsigned)(val * 32767.f + 0.5f);
}

// ---------------------------------------------------------------------------
// Kernel 1: pack W[256][64] (fp32) into MFMA B-fragment order, bf16.
// ---------------------------------------------------------------------------
__global__ __launch_bounds__(256) void pack_w(const float* __restrict__ W,
                                              bf16_t* __restrict__ Wpack) {
    int id = blockIdx.x * 256 + threadIdx.x;
    if (id < D_IN * D_OUT) {
        int i  = id & 7;
        int l  = (id >> 3) & 63;
        int n  = (id >> 9) & 3;
        int kk = id >> 11;
        int k = kk * 32 + (l >> 4) * 8 + i;
        int c = n * 16 + (l & 15);
        Wpack[id] = (bf16_t)W[k * D_OUT + c];
    }
}

// ---- GEMM helpers: explicit load-all / compute / store per 16-row tile ----
__device__ __forceinline__ void load_tile16(const float* __restrict__ xp,
                                            float4* buf) {
#pragma unroll
    for (int q = 0; q < 16; ++q)
        buf[q] = *(const float4*)(xp + (q >> 1) * 32 + (q & 1) * 4);
}

__device__ __forceinline__ void compute_store_tile(
        const float4* buf, const bf16x8* Wl, int lane, int lrow, int g,
        bf16_t* __restrict__ support, int tile, bool valid) {
    f32x4 c0 = {0.f, 0.f, 0.f, 0.f}, c1 = c0, c2 = c0, c3 = c0;
#pragma unroll
    for (int kk = 0; kk < 8; ++kk) {
        float4 lo = buf[2 * kk], hi = buf[2 * kk + 1];
        bf16x8 a;
        a[0] = (bf16_t)lo.x; a[1] = (bf16_t)lo.y;
        a[2] = (bf16_t)lo.z; a[3] = (bf16_t)lo.w;
        a[4] = (bf16_t)hi.x; a[5] = (bf16_t)hi.y;
        a[6] = (bf16_t)hi.z; a[7] = (bf16_t)hi.w;
        bf16x8 w0 = Wl[(kk * 4 + 0) * 64 + lane];
        bf16x8 w1 = Wl[(kk * 4 + 1) * 64 + lane];
        bf16x8 w2 = Wl[(kk * 4 + 2) * 64 + lane];
        bf16x8 w3 = Wl[(kk * 4 + 3) * 64 + lane];
        c0 = __builtin_amdgcn_mfma_f32_16x16x32_bf16(a, w0, c0, 0, 0, 0);
        c1 = __builtin_amdgcn_mfma_f32_16x16x32_bf16(a, w1, c1, 0, 0, 0);
        c2 = __builtin_amdgcn_mfma_f32_16x16x32_bf16(a, w2, c2, 0, 0, 0);
        c3 = __builtin_amdgcn_mfma_f32_16x16x32_bf16(a, w3, c3, 0, 0, 0);
    }
    if (valid) {
        bf16_t* __restrict__ sp = support + (size_t)tile * 16 * D_OUT;
#pragma unroll
        for (int q = 0; q < 4; ++q) {
            int row = g * 4 + q;
            sp[row * D_OUT +  0 + lrow] = (bf16_t)c0[q];
            sp[row * D_OUT + 16 + lrow] = (bf16_t)c1[q];
            sp[row * D_OUT + 32 + lrow] = (bf16_t)c2[q];
            sp[row * D_OUT + 48 + lrow] = (bf16_t)c3[q];
        }
    }
}

// ---------------------------------------------------------------------------
// Kernel 2 (fused, striped): period-4 block roles -> 1 GEMM : 3 edge.
// GEMM role: 4 tiles/wave, two-buffer pipeline (issue tile t+1's 16
// dwordx4 loads, then convert+MFMA+store tile t) -> ~16 loads always in
// flight per wave. W fragments staged once in LDS. Edge role: histogram
// + cv pack, co-resident with GEMM.
// ---------------------------------------------------------------------------
__global__ __launch_bounds__(256, 2) void gemm_hist_cv(
        const float* __restrict__ x, const bf16x8* __restrict__ Wpack,
        bf16_t* __restrict__ support,
        const int* __restrict__ erow, const int* __restrict__ ecol,
        const float* __restrict__ eval,
        int* __restrict__ counts, unsigned* __restrict__ cv) {
    __shared__ bf16x8 Wlds[2048];                  // 32 KB
    int p = blockIdx.x >> 2;
    int r = blockIdx.x & 3;
    if (r == 0) {
        // ---------------- GEMM role ----------------
        {
            int t = threadIdx.x;
#pragma unroll
            for (int i = 0; i < 8; ++i)
                Wlds[t + i * 256] = Wpack[t + i * 256];
        }
        __syncthreads();

        int wave = threadIdx.x >> 6;
        int lane = threadIdx.x & 63;
        int lrow = lane & 15;
        int g    = lane >> 4;
        int tbase = p * TILES_PER_BLOCK + wave * 4;

        int  t0 = tbase + 0, t1 = tbase + 1, t2 = tbase + 2, t3 = tbase + 3;
        bool v0 = t0 < N_TILES, v1 = t1 < N_TILES, v2 = t2 < N_TILES, v3 = t3 < N_TILES;
        int  s0 = v0 ? t0 : 0, s1 = v1 ? t1 : 0, s2 = v2 ? t2 : 0, s3 = v3 ? t3 : 0;
        const float* xp0 = x + (size_t)(s0 * 16 + lrow) * D_IN + g * 8;
        const float* xp1 = x + (size_t)(s1 * 16 + lrow) * D_IN + g * 8;
        const float* xp2 = x + (size_t)(s2 * 16 + lrow) * D_IN + g * 8;
        const float* xp3 = x + (size_t)(s3 * 16 + lrow) * D_IN + g * 8;

        float4 bufA[16], bufB[16];
        load_tile16(xp0, bufA);
        load_tile16(xp1, bufB);
        compute_store_tile(bufA, Wlds, lane, lrow, g, support, s0, v0);
        load_tile16(xp2, bufA);
        compute_store_tile(bufB, Wlds, lane, lrow, g, support, s1, v1);
        load_tile16(xp3, bufB);
        compute_store_tile(bufA, Wlds, lane, lrow, g, support, s2, v2);
        compute_store_tile(bufB, Wlds, lane, lrow, g, support, s3, v3);
    } else {
        // ---------------- edge role: histogram + cv pack ----------------
        int eb = p * 3 + (r - 1);                  // 0..1172
        if (eb >= EDGE4_NB) return;
        int e = (eb * 256 + threadIdx.x) * 4;
        if (e + 3 < N_EDGES) {
            int4   r4 = *(const int4*)(erow + e);
            int4   c4 = *(const int4*)(ecol + e);
            float4 v4 = *(const float4*)(eval + e);
            atomicAdd(&counts[r4.x], 1);
            atomicAdd(&counts[r4.y], 1);
            atomicAdd(&counts[r4.z], 1);
            atomicAdd(&counts[r4.w], 1);
            uint4 o;
            o.x = pack_cv(c4.x, v4.x);
            o.y = pack_cv(c4.y, v4.y);
            o.z = pack_cv(c4.z, v4.z);
            o.w = pack_cv(c4.w, v4.w);
            *(uint4*)(cv + e) = o;
        } else {
            for (int i = 0; i < 4; ++i) {
                if (e + i < N_EDGES) {
                    atomicAdd(&counts[erow[e + i]], 1);
                    cv[e + i] = pack_cv(ecol[e + i], eval[e + i]);
                }
            }
        }
    }
}

// ---------------------------------------------------------------------------
// Kernel 3a: per-block partial sums of counts (1024 counts per block).
// ---------------------------------------------------------------------------
__global__ __launch_bounds__(256) void partial_k(const int* __restrict__ counts,
                                                 int* __restrict__ bsum) {
    int b = blockIdx.x, t = threadIdx.x;
    int base = b * SCAN_BLOCK + t * 4;
    int s = 0;
    if (base + 3 < N_NODES) {
        int4 v = *(const int4*)(counts + base);
        s = v.x + v.y + v.z + v.w;
    } else {
#pragma unroll
        for (int i = 0; i < 4; ++i)
            if (base + i < N_NODES) s += counts[base + i];
    }
#pragma unroll
    for (int off = 32; off > 0; off >>= 1) s += __shfl_down(s, off);
    __shared__ int sh[4];
    if ((t & 63) == 0) sh[t >> 6] = s;
    __syncthreads();
    if (t == 0) bsum[b] = sh[0] + sh[1] + sh[2] + sh[3];
}

// ---------------------------------------------------------------------------
// Kernel 3b: scan the 98 block sums (1 tiny block). Also writes offsets[N].
// ---------------------------------------------------------------------------
__global__ __launch_bounds__(128) void scan_bsum_k(const int* __restrict__ bsum,
                                                   int* __restrict__ bpre,
                                                   int* __restrict__ offsets) {
    __shared__ int sh[128];
    int t = threadIdx.x;
    int v = (t < SCAN_NB) ? bsum[t] : 0;
    sh[t] = v;
    __syncthreads();
    for (int off = 1; off < 128; off <<= 1) {
        int add = (t >= off) ? sh[t - off] : 0;
        __syncthreads();
        sh[t] += add;
        __syncthreads();
    }
    if (t < SCAN_NB) bpre[t] = sh[t] - v;
    if (t == 127) offsets[N_NODES] = sh[127];
}

// ---------------------------------------------------------------------------
// Kernel 3c: block-local scan + global prefix -> offsets, cursor.
// ---------------------------------------------------------------------------
__global__ __launch_bounds__(256) void emit_k(const int* __restrict__ counts,
                                              const int* __restrict__ bpre,
                                              int* __restrict__ offsets,
                                              int* __restrict__ cursor) {
    __shared__ int sh[256];
    int b = blockIdx.x, t = threadIdx.x;
    int base = b * SCAN_BLOCK + t * 4;
    int c0 = 0, c1 = 0, c2 = 0, c3 = 0;
    if (base + 3 < N_NODES) {
        int4 v = *(const int4*)(counts + base);
        c0 = v.x; c1 = v.y; c2 = v.z; c3 = v.w;
    } else {
        if (base + 0 < N_NODES) c0 = counts[base + 0];
        if (base + 1 < N_NODES) c1 = counts[base + 1];
        if (base + 2 < N_NODES) c2 = counts[base + 2];
        if (base + 3 < N_NODES) c3 = counts[base + 3];
    }
    int sum4 = c0 + c1 + c2 + c3;
    sh[t] = sum4;
    __syncthreads();
    for (int off = 1; off < 256; off <<= 1) {
        int add = (t >= off) ? sh[t - off] : 0;
        __syncthreads();
        sh[t] += add;
        __syncthreads();
    }
    int run = bpre[b] + sh[t] - sum4;
    if (base + 0 < N_NODES) { offsets[base + 0] = run; cursor[base + 0] = run; run += c0; }
    if (base + 1 < N_NODES) { offsets[base + 1] = run; cursor[base + 1] = run; run += c1; }
    if (base + 2 < N_NODES) { offsets[base + 2] = run; cursor[base + 2] = run; run += c2; }
    if (base + 3 < N_NODES) { offsets[base + 3] = run; cursor[base + 3] = run; run += c3; }
}

// ---------------------------------------------------------------------------
// Kernel 4: predicated CSR fill, one pass per row range [lo, hi).
// Writes land in a 2.4 MB csr window -> per-XCD-L2-resident.
// ---------------------------------------------------------------------------
__global__ __launch_bounds__(256) void fill_k(const int* __restrict__ erow,
                                              const unsigned* __restrict__ cv,
                                              int* __restrict__ cursor,
                                              unsigned* __restrict__ csr,
                                              int lo, int hi) {
    int t = blockIdx.x * 256 + threadIdx.x;
    int e = t * 4;
    if (e + 3 < N_EDGES) {
        int4  r4 = *(const int4*)(erow + e);
        uint4 c4 = *(const uint4*)(cv + e);
        if (r4.x >= lo && r4.x < hi) { int q = atomicAdd(&cursor[r4.x], 1); csr[q] = c4.x; }
        if (r4.y >= lo && r4.y < hi) { int q = atomicAdd(&cursor[r4.y], 1); csr[q] = c4.y; }
        if (r4.z >= lo && r4.z < hi) { int q = atomicAdd(&cursor[r4.z], 1); csr[q] = c4.z; }
        if (r4.w >= lo && r4.w < hi) { int q = atomicAdd(&cursor[r4.w], 1); csr[q] = c4.w; }
    } else {
        for (int i = 0; i < 4; ++i) {
            if (e + i < N_EDGES) {
                int rr = erow[e + i];
                if (rr >= lo && rr < hi) {
                    int q = atomicAdd(&cursor[rr], 1);
                    csr[q] = cv[e + i];
                }
            }
        }
    }
}

// ---------------------------------------------------------------------------
// Kernel 5: aggregate + ReLU. One wave per node, lane = feature.
// 8-deep ILP: 8 independent csr loads then 8 independent support gathers.
// ---------------------------------------------------------------------------
__global__ __launch_bounds__(256) void agg_k(const int* __restrict__ offsets,
                                             const unsigned* __restrict__ csr,
                                             const bf16_t* __restrict__ support,
                                             float* __restrict__ out) {
    int node = blockIdx.x * 4 + (threadIdx.x >> 6);
    int lane = threadIdx.x & 63;
    if (node >= N_NODES) return;
    int s = offsets[node];
    int e = offsets[node + 1];
    const float inv = 1.f / 32767.f;
    float acc = 0.f;
    int p = s;
    for (; p + 8 <= e; p += 8) {
        unsigned w0 = csr[p + 0], w1 = csr[p + 1], w2 = csr[p + 2], w3 = csr[p + 3];
        unsigned w4 = csr[p + 4], w5 = csr[p + 5], w6 = csr[p + 6], w7 = csr[p + 7];
        float s0 = (float)support[(size_t)(w0 >> 15) * D_OUT + lane];
        float s1 = (float)support[(size_t)(w1 >> 15) * D_OUT + lane];
        float s2 = (float)support[(size_t)(w2 >> 15) * D_OUT + lane];
        float s3 = (float)support[(size_t)(w3 >> 15) * D_OUT + lane];
        float s4 = (float)support[(size_t)(w4 >> 15) * D_OUT + lane];
        float s5 = (float)support[(size_t)(w5 >> 15) * D_OUT + lane];
        float s6 = (float)support[(size_t)(w6 >> 15) * D_OUT + lane];
        float s7 = (float)support[(size_t)(w7 >> 15) * D_OUT + lane];
        acc = fmaf((float)(w0 & 0x7fffu) * inv, s0, acc);
        acc = fmaf((float)(w1 & 0x7fffu) * inv, s1, acc);
        acc = fmaf((float)(w2 & 0x7fffu) * inv, s2, acc);
        acc = fmaf((float)(w3 & 0x7fffu) * inv, s3, acc);
        acc = fmaf((float)(w4 & 0x7fffu) * inv, s4, acc);
        acc = fmaf((float)(w5 & 0x7fffu) * inv, s5, acc);
        acc = fmaf((float)(w6 & 0x7fffu) * inv, s6, acc);
        acc = fmaf((float)(w7 & 0x7fffu) * inv, s7, acc);
    }
    for (; p + 4 <= e; p += 4) {
        unsigned w0 = csr[p + 0], w1 = csr[p + 1], w2 = csr[p + 2], w3 = csr[p + 3];
        float s0 = (float)support[(size_t)(w0 >> 15) * D_OUT + lane];
        float s1 = (float)support[(size_t)(w1 >> 15) * D_OUT + lane];
        float s2 = (float)support[(size_t)(w2 >> 15) * D_OUT + lane];
        float s3 = (float)support[(size_t)(w3 >> 15) * D_OUT + lane];
        acc = fmaf((float)(w0 & 0x7fffu) * inv, s0, acc);
        acc = fmaf((float)(w1 & 0x7fffu) * inv, s1, acc);
        acc = fmaf((float)(w2 & 0x7fffu) * inv, s2, acc);
        acc = fmaf((float)(w3 & 0x7fffu) * inv, s3, acc);
    }
    for (; p < e; ++p) {
        unsigned w = csr[p];
        acc = fmaf((float)(w & 0x7fffu) * inv,
                   (float)support[(size_t)(w >> 15) * D_OUT + lane], acc);
    }
    out[(size_t)node * D_OUT + lane] = fmaxf(acc, 0.f);
}

extern "C" void kernel_launch(void* const* d_in, const int* in_sizes, int n_in,
                              void* d_out, int out_size, void* d_ws, size_t ws_size,
                              hipStream_t stream) {
    const float* x    = (const float*)d_in[0];
    const int*   erow = (const int*)d_in[1];
    const int*   ecol = (const int*)d_in[2];
    const float* eval = (const float*)d_in[3];
    const float* W    = (const float*)d_in[4];
    float* out = (float*)d_out;

    // ---- workspace layout (16B-aligned segments, ~23.6 MB) ----
    char* ws = (char*)d_ws;
    bf16_t*   support = (bf16_t*)ws;                         // 12,800,000
    bf16_t*   WpackS  = (bf16_t*)(ws + 12800000);            //     32,768
    int*      counts  = (int*)(ws + 12832768);               //    400,000
    int*      offsets = (int*)(ws + 13232768);               //    400,004
    int*      cursor  = (int*)(ws + 13632896);               //    400,000
    unsigned* cv      = (unsigned*)(ws + 14032896);          //  4,800,000
    unsigned* csr     = (unsigned*)(ws + 18832896);          //  4,800,000
    int*      bsum    = (int*)(ws + 23632896);               //        392
    int*      bpre    = (int*)(ws + 23633288);               //        392

    // 1) pack W into bf16 MFMA B-fragments
    pack_w<<<(D_IN * D_OUT + 255) / 256, 256, 0, stream>>>(W, WpackS);

    // 2) zero counts, then fused (striped) GEMM + histogram + cv pack
    hipMemsetAsync(counts, 0, (size_t)N_NODES * sizeof(int), stream);
    gemm_hist_cv<<<FUSED_NB, 256, 0, stream>>>(
        x, (const bf16x8*)WpackS, support, erow, ecol, eval, counts, cv);

    // 3) hierarchical scan -> offsets, cursor
    partial_k<<<SCAN_NB, 256, 0, stream>>>(counts, bsum);
    scan_bsum_k<<<1, 128, 0, stream>>>(bsum, bpre, offsets);
    emit_k<<<SCAN_NB, 256, 0, stream>>>(counts, bpre, offsets, cursor);

    // 4) predicated CSR fill, 2 L2-localized passes
    for (int p = 0; p < FILL_PASSES; ++p) {
        fill_k<<<FILL_NB, 256, 0, stream>>>(erow, cv, cursor, csr,
                                            p * PASS_NODES, (p + 1) * PASS_NODES);
    }

    // 5) aggregate + ReLU (no atomics, writes every output element)
    agg_k<<<(N_NODES + 3) / 4, 256, 0, stream>>>(offsets, csr, support, out);
}

// Round 8
// 184.845 us; speedup vs baseline: 1.1385x; 1.1385x over previous
//
#include <hip/hip_runtime.h>
#include <hip/hip_bf16.h>

#define N_NODES 100000
#define N_EDGES 1200000
#define D_IN 256
#define D_OUT 64
#define N_TILES (N_NODES / 16)                     // 6250 row tiles of 16

// fused kernel striping: period 5 = 2 GEMM blocks + 3 edge blocks
#define TILES_PER_BLOCK 8                          // 4 waves x 2 tiles
#define GEMM_NB ((N_TILES + TILES_PER_BLOCK - 1) / TILES_PER_BLOCK) // 782
#define EDGE4_NB ((N_EDGES / 4 + 255) / 256)       // 1172 (4 edges/thread)
#define STRIPE_P ((GEMM_NB + 1) / 2)               // 391 periods
#define FUSED_NB (STRIPE_P * 5)                    // 1955

#define FILL_PASSES 2
#define PASS_NODES (N_NODES / FILL_PASSES)         // 50000
#define FILL_NB EDGE4_NB

#define SCAN_BLOCK 1024
#define SCAN_NB ((N_NODES + SCAN_BLOCK - 1) / SCAN_BLOCK) // 98

#define TB_PITCH 136                               // 64 bf16 = 128B + 8B pad
#define TB_SIZE  (16 * TB_PITCH)                   // 2176 B per wave

typedef __bf16 bf16_t;
typedef bf16_t bf16x8 __attribute__((ext_vector_type(8)));
typedef float f32x4 __attribute__((ext_vector_type(4)));

// pack (col, val) into 4B: col<<15 | round(val*32767). val in [0,1).
__device__ __forceinline__ unsigned pack_cv(int col, float val) {
    return ((unsigned)col << 15) | (unsigned)(val * 32767.f + 0.5f);
}

__device__ __forceinline__ bf16x8 cvt8(float4 lo, float4 hi) {
    bf16x8 a;
    a[0] = (bf16_t)lo.x; a[1] = (bf16_t)lo.y;
    a[2] = (bf16_t)lo.z; a[3] = (bf16_t)lo.w;
    a[4] = (bf16_t)hi.x; a[5] = (bf16_t)hi.y;
    a[6] = (bf16_t)hi.z; a[7] = (bf16_t)hi.w;
    return a;
}

// ---------------------------------------------------------------------------
// Kernel 1: pack W[256][64] (fp32) into MFMA B-fragment order, bf16.
// ---------------------------------------------------------------------------
__global__ __launch_bounds__(256) void pack_w(const float* __restrict__ W,
                                              bf16_t* __restrict__ Wpack) {
    int id = blockIdx.x * 256 + threadIdx.x;
    if (id < D_IN * D_OUT) {
        int i  = id & 7;
        int l  = (id >> 3) & 63;
        int n  = (id >> 9) & 3;
        int kk = id >> 11;
        int k = kk * 32 + (l >> 4) * 8 + i;
        int c = n * 16 + (l & 15);
        Wpack[id] = (bf16_t)W[k * D_OUT + c];
    }
}

// Epilogue: acc -> per-wave LDS tile (padded) -> coalesced contiguous stores.
// C/D layout (m89): col = lane&15 (lrow), row = (lane>>4)*4 + reg (g*4+q).
__device__ __forceinline__ void epilogue_tile(
        char* tbw, int lane, int lrow, int g,
        const f32x4& c0, const f32x4& c1, const f32x4& c2, const f32x4& c3,
        bf16_t* __restrict__ support, int tile, bool valid) {
    if (!valid) return;   // wave-uniform
#pragma unroll
    for (int q = 0; q < 4; ++q) {
        char* rowp = tbw + (g * 4 + q) * TB_PITCH + lrow * 2;
        *(bf16_t*)(rowp +  0) = (bf16_t)c0[q];
        *(bf16_t*)(rowp + 32) = (bf16_t)c1[q];
        *(bf16_t*)(rowp + 64) = (bf16_t)c2[q];
        *(bf16_t*)(rowp + 96) = (bf16_t)c3[q];
    }
    asm volatile("s_waitcnt lgkmcnt(0)" ::: "memory");
    int r  = lane >> 2;
    int cb = (lane & 3) * 32;
    uint4 lo = *(const uint4*)(tbw + r * TB_PITCH + cb);
    uint4 hi = *(const uint4*)(tbw + r * TB_PITCH + cb + 16);
    char* dst = (char*)support + (size_t)tile * 2048 + r * 128 + cb;
    *(uint4*)dst = lo;
    *(uint4*)(dst + 16) = hi;
}

// ---------------------------------------------------------------------------
// Kernel 2 (fused, striped): period-5 block roles -> 2 GEMM : 3 edge.
// GEMM role: 2 tiles/wave interleaved per kk; explicit distance-2 rotating
// register prefetch over kk (8 float4 in flight); W fragments in LDS;
// LDS-transpose epilogue for contiguous support stores.
// Edge role: histogram + cv pack, co-resident with GEMM.
// ---------------------------------------------------------------------------
__global__ __launch_bounds__(256, 3) void gemm_hist_cv(
        const float* __restrict__ x, const bf16x8* __restrict__ Wpack,
        bf16_t* __restrict__ support,
        const int* __restrict__ erow, const int* __restrict__ ecol,
        const float* __restrict__ eval,
        int* __restrict__ counts, unsigned* __restrict__ cv) {
    __shared__ bf16x8 Wlds[2048];                  // 32 KB
    __shared__ char   tb[4][TB_SIZE];              // 8.5 KB transpose buffers
    int p = blockIdx.x / 5;
    int r = blockIdx.x % 5;
    if (r < 2) {
        // ---------------- GEMM role ----------------
        int gb = p * 2 + r;                        // 0..781
        {
            int t = threadIdx.x;
#pragma unroll
            for (int i = 0; i < 8; ++i)
                Wlds[t + i * 256] = Wpack[t + i * 256];
        }
        __syncthreads();

        int wave = threadIdx.x >> 6;
        int lane = threadIdx.x & 63;
        int lrow = lane & 15;
        int g    = lane >> 4;
        int tileA = gb * TILES_PER_BLOCK + wave * 2;
        int tileB = tileA + 1;
        bool vA = (tileA < N_TILES);
        bool vB = (tileB < N_TILES);
        int tA = vA ? tileA : 0;
        int tB = vB ? tileB : 0;

        const float* __restrict__ xpA = x + (size_t)(tA * 16 + lrow) * D_IN + g * 8;
        const float* __restrict__ xpB = x + (size_t)(tB * 16 + lrow) * D_IN + g * 8;

        f32x4 a0 = {0.f,0.f,0.f,0.f}, a1 = a0, a2 = a0, a3 = a0;
        f32x4 b0 = a0, b1 = a0, b2 = a0, b3 = a0;

        // rotating 2-slot register prefetch, distance 2 over kk
        float4 sA0[2], sA1[2], sB0[2], sB1[2];
        sA0[0] = *(const float4*)(xpA +  0);
        sA1[0] = *(const float4*)(xpA +  4);
        sB0[0] = *(const float4*)(xpB +  0);
        sB1[0] = *(const float4*)(xpB +  4);
        sA0[1] = *(const float4*)(xpA + 32);
        sA1[1] = *(const float4*)(xpA + 36);
        sB0[1] = *(const float4*)(xpB + 32);
        sB1[1] = *(const float4*)(xpB + 36);

#pragma unroll
        for (int kk = 0; kk < 8; ++kk) {
            const int s = kk & 1;
            bf16x8 aA = cvt8(sA0[s], sA1[s]);
            bf16x8 aB = cvt8(sB0[s], sB1[s]);
            if (kk < 6) {   // prefetch kk+2 into freed slot, before MFMAs
                sA0[s] = *(const float4*)(xpA + (kk + 2) * 32);
                sA1[s] = *(const float4*)(xpA + (kk + 2) * 32 + 4);
                sB0[s] = *(const float4*)(xpB + (kk + 2) * 32);
                sB1[s] = *(const float4*)(xpB + (kk + 2) * 32 + 4);
            }
            bf16x8 w0 = Wlds[(kk * 4 + 0) * 64 + lane];
            bf16x8 w1 = Wlds[(kk * 4 + 1) * 64 + lane];
            bf16x8 w2 = Wlds[(kk * 4 + 2) * 64 + lane];
            bf16x8 w3 = Wlds[(kk * 4 + 3) * 64 + lane];

            a0 = __builtin_amdgcn_mfma_f32_16x16x32_bf16(aA, w0, a0, 0, 0, 0);
            a1 = __builtin_amdgcn_mfma_f32_16x16x32_bf16(aA, w1, a1, 0, 0, 0);
            a2 = __builtin_amdgcn_mfma_f32_16x16x32_bf16(aA, w2, a2, 0, 0, 0);
            a3 = __builtin_amdgcn_mfma_f32_16x16x32_bf16(aA, w3, a3, 0, 0, 0);
            b0 = __builtin_amdgcn_mfma_f32_16x16x32_bf16(aB, w0, b0, 0, 0, 0);
            b1 = __builtin_amdgcn_mfma_f32_16x16x32_bf16(aB, w1, b1, 0, 0, 0);
            b2 = __builtin_amdgcn_mfma_f32_16x16x32_bf16(aB, w2, b2, 0, 0, 0);
            b3 = __builtin_amdgcn_mfma_f32_16x16x32_bf16(aB, w3, b3, 0, 0, 0);
        }

        char* tbw = tb[wave];
        epilogue_tile(tbw, lane, lrow, g, a0, a1, a2, a3, support, tA, vA);
        epilogue_tile(tbw, lane, lrow, g, b0, b1, b2, b3, support, tB, vB);
    } else {
        // ---------------- edge role: histogram + cv pack ----------------
        int eb = p * 3 + (r - 2);                  // 0..1171
        if (eb >= EDGE4_NB) return;
        int e = (eb * 256 + threadIdx.x) * 4;
        if (e + 3 < N_EDGES) {
            int4   r4 = *(const int4*)(erow + e);
            int4   c4 = *(const int4*)(ecol + e);
            float4 v4 = *(const float4*)(eval + e);
            atomicAdd(&counts[r4.x], 1);
            atomicAdd(&counts[r4.y], 1);
            atomicAdd(&counts[r4.z], 1);
            atomicAdd(&counts[r4.w], 1);
            uint4 o;
            o.x = pack_cv(c4.x, v4.x);
            o.y = pack_cv(c4.y, v4.y);
            o.z = pack_cv(c4.z, v4.z);
            o.w = pack_cv(c4.w, v4.w);
            *(uint4*)(cv + e) = o;
        } else {
            for (int i = 0; i < 4; ++i) {
                if (e + i < N_EDGES) {
                    atomicAdd(&counts[erow[e + i]], 1);
                    cv[e + i] = pack_cv(ecol[e + i], eval[e + i]);
                }
            }
        }
    }
}

// ---------------------------------------------------------------------------
// Kernel 3a: per-block partial sums of counts (1024 counts per block).
// ---------------------------------------------------------------------------
__global__ __launch_bounds__(256) void partial_k(const int* __restrict__ counts,
                                                 int* __restrict__ bsum) {
    int b = blockIdx.x, t = threadIdx.x;
    int base = b * SCAN_BLOCK + t * 4;
    int s = 0;
    if (base + 3 < N_NODES) {
        int4 v = *(const int4*)(counts + base);
        s = v.x + v.y + v.z + v.w;
    } else {
#pragma unroll
        for (int i = 0; i < 4; ++i)
            if (base + i < N_NODES) s += counts[base + i];
    }
#pragma unroll
    for (int off = 32; off > 0; off >>= 1) s += __shfl_down(s, off);
    __shared__ int sh[4];
    if ((t & 63) == 0) sh[t >> 6] = s;
    __syncthreads();
    if (t == 0) bsum[b] = sh[0] + sh[1] + sh[2] + sh[3];
}

// ---------------------------------------------------------------------------
// Kernel 3b: scan the 98 block sums (1 tiny block). Also writes offsets[N].
// ---------------------------------------------------------------------------
__global__ __launch_bounds__(128) void scan_bsum_k(const int* __restrict__ bsum,
                                                   int* __restrict__ bpre,
                                                   int* __restrict__ offsets) {
    __shared__ int sh[128];
    int t = threadIdx.x;
    int v = (t < SCAN_NB) ? bsum[t] : 0;
    sh[t] = v;
    __syncthreads();
    for (int off = 1; off < 128; off <<= 1) {
        int add = (t >= off) ? sh[t - off] : 0;
        __syncthreads();
        sh[t] += add;
        __syncthreads();
    }
    if (t < SCAN_NB) bpre[t] = sh[t] - v;
    if (t == 127) offsets[N_NODES] = sh[127];
}

// ---------------------------------------------------------------------------
// Kernel 3c: block-local scan + global prefix -> offsets, cursor.
// ---------------------------------------------------------------------------
__global__ __launch_bounds__(256) void emit_k(const int* __restrict__ counts,
                                              const int* __restrict__ bpre,
                                              int* __restrict__ offsets,
                                              int* __restrict__ cursor) {
    __shared__ int sh[256];
    int b = blockIdx.x, t = threadIdx.x;
    int base = b * SCAN_BLOCK + t * 4;
    int c0 = 0, c1 = 0, c2 = 0, c3 = 0;
    if (base + 3 < N_NODES) {
        int4 v = *(const int4*)(counts + base);
        c0 = v.x; c1 = v.y; c2 = v.z; c3 = v.w;
    } else {
        if (base + 0 < N_NODES) c0 = counts[base + 0];
        if (base + 1 < N_NODES) c1 = counts[base + 1];
        if (base + 2 < N_NODES) c2 = counts[base + 2];
        if (base + 3 < N_NODES) c3 = counts[base + 3];
    }
    int sum4 = c0 + c1 + c2 + c3;
    sh[t] = sum4;
    __syncthreads();
    for (int off = 1; off < 256; off <<= 1) {
        int add = (t >= off) ? sh[t - off] : 0;
        __syncthreads();
        sh[t] += add;
        __syncthreads();
    }
    int run = bpre[b] + sh[t] - sum4;
    if (base + 0 < N_NODES) { offsets[base + 0] = run; cursor[base + 0] = run; run += c0; }
    if (base + 1 < N_NODES) { offsets[base + 1] = run; cursor[base + 1] = run; run += c1; }
    if (base + 2 < N_NODES) { offsets[base + 2] = run; cursor[base + 2] = run; run += c2; }
    if (base + 3 < N_NODES) { offsets[base + 3] = run; cursor[base + 3] = run; run += c3; }
}

// ---------------------------------------------------------------------------
// Kernel 4: predicated CSR fill, one pass per row range [lo, hi).
// ---------------------------------------------------------------------------
__global__ __launch_bounds__(256) void fill_k(const int* __restrict__ erow,
                                              const unsigned* __restrict__ cv,
                                              int* __restrict__ cursor,
                                              unsigned* __restrict__ csr,
                                              int lo, int hi) {
    int t = blockIdx.x * 256 + threadIdx.x;
    int e = t * 4;
    if (e + 3 < N_EDGES) {
        int4  r4 = *(const int4*)(erow + e);
        uint4 c4 = *(const uint4*)(cv + e);
        if (r4.x >= lo && r4.x < hi) { int q = atomicAdd(&cursor[r4.x], 1); csr[q] = c4.x; }
        if (r4.y >= lo && r4.y < hi) { int q = atomicAdd(&cursor[r4.y], 1); csr[q] = c4.y; }
        if (r4.z >= lo && r4.z < hi) { int q = atomicAdd(&cursor[r4.z], 1); csr[q] = c4.z; }
        if (r4.w >= lo && r4.w < hi) { int q = atomicAdd(&cursor[r4.w], 1); csr[q] = c4.w; }
    } else {
        for (int i = 0; i < 4; ++i) {
            if (e + i < N_EDGES) {
                int rr = erow[e + i];
                if (rr >= lo && rr < hi) {
                    int q = atomicAdd(&cursor[rr], 1);
                    csr[q] = cv[e + i];
                }
            }
        }
    }
}

// ---------------------------------------------------------------------------
// Kernel 5: aggregate + ReLU. One wave per node, lane = feature.
// ---------------------------------------------------------------------------
__global__ __launch_bounds__(256) void agg_k(const int* __restrict__ offsets,
                                             const unsigned* __restrict__ csr,
                                             const bf16_t* __restrict__ support,
                                             float* __restrict__ out) {
    int node = blockIdx.x * 4 + (threadIdx.x >> 6);
    int lane = threadIdx.x & 63;
    if (node >= N_NODES) return;
    int s = offsets[node];
    int e = offsets[node + 1];
    const float inv = 1.f / 32767.f;
    float acc = 0.f;
    int p = s;
    for (; p + 8 <= e; p += 8) {
        unsigned w0 = csr[p + 0], w1 = csr[p + 1], w2 = csr[p + 2], w3 = csr[p + 3];
        unsigned w4 = csr[p + 4], w5 = csr[p + 5], w6 = csr[p + 6], w7 = csr[p + 7];
        float s0 = (float)support[(size_t)(w0 >> 15) * D_OUT + lane];
        float s1 = (float)support[(size_t)(w1 >> 15) * D_OUT + lane];
        float s2 = (float)support[(size_t)(w2 >> 15) * D_OUT + lane];
        float s3 = (float)support[(size_t)(w3 >> 15) * D_OUT + lane];
        float s4 = (float)support[(size_t)(w4 >> 15) * D_OUT + lane];
        float s5 = (float)support[(size_t)(w5 >> 15) * D_OUT + lane];
        float s6 = (float)support[(size_t)(w6 >> 15) * D_OUT + lane];
        float s7 = (float)support[(size_t)(w7 >> 15) * D_OUT + lane];
        acc = fmaf((float)(w0 & 0x7fffu) * inv, s0, acc);
        acc = fmaf((float)(w1 & 0x7fffu) * inv, s1, acc);
        acc = fmaf((float)(w2 & 0x7fffu) * inv, s2, acc);
        acc = fmaf((float)(w3 & 0x7fffu) * inv, s3, acc);
        acc = fmaf((float)(w4 & 0x7fffu) * inv, s4, acc);
        acc = fmaf((float)(w5 & 0x7fffu) * inv, s5, acc);
        acc = fmaf((float)(w6 & 0x7fffu) * inv, s6, acc);
        acc = fmaf((float)(w7 & 0x7fffu) * inv, s7, acc);
    }
    for (; p + 4 <= e; p += 4) {
        unsigned w0 = csr[p + 0], w1 = csr[p + 1], w2 = csr[p + 2], w3 = csr[p + 3];
        float s0 = (float)support[(size_t)(w0 >> 15) * D_OUT + lane];
        float s1 = (float)support[(size_t)(w1 >> 15) * D_OUT + lane];
        float s2 = (float)support[(size_t)(w2 >> 15) * D_OUT + lane];
        float s3 = (float)support[(size_t)(w3 >> 15) * D_OUT + lane];
        acc = fmaf((float)(w0 & 0x7fffu) * inv, s0, acc);
        acc = fmaf((float)(w1 & 0x7fffu) * inv, s1, acc);
        acc = fmaf((float)(w2 & 0x7fffu) * inv, s2, acc);
        acc = fmaf((float)(w3 & 0x7fffu) * inv, s3, acc);
    }
    for (; p < e; ++p) {
        unsigned w = csr[p];
        acc = fmaf((float)(w & 0x7fffu) * inv,
                   (float)support[(size_t)(w >> 15) * D_OUT + lane], acc);
    }
    out[(size_t)node * D_OUT + lane] = fmaxf(acc, 0.f);
}

extern "C" void kernel_launch(void* const* d_in, const int* in_sizes, int n_in,
                              void* d_out, int out_size, void* d_ws, size_t ws_size,
                              hipStream_t stream) {
    const float* x    = (const float*)d_in[0];
    const int*   erow = (const int*)d_in[1];
    const int*   ecol = (const int*)d_in[2];
    const float* eval = (const float*)d_in[3];
    const float* W    = (const float*)d_in[4];
    float* out = (float*)d_out;

    // ---- workspace layout (16B-aligned segments, ~23.6 MB) ----
    char* ws = (char*)d_ws;
    bf16_t*   support = (bf16_t*)ws;                         // 12,800,000
    bf16_t*   WpackS  = (bf16_t*)(ws + 12800000);            //     32,768
    int*      counts  = (int*)(ws + 12832768);               //    400,000
    int*      offsets = (int*)(ws + 13232768);               //    400,004
    int*      cursor  = (int*)(ws + 13632896);               //    400,000
    unsigned* cv      = (unsigned*)(ws + 14032896);          //  4,800,000
    unsigned* csr     = (unsigned*)(ws + 18832896);          //  4,800,000
    int*      bsum    = (int*)(ws + 23632896);               //        392
    int*      bpre    = (int*)(ws + 23633288);               //        392

    // 1) pack W into bf16 MFMA B-fragments
    pack_w<<<(D_IN * D_OUT + 255) / 256, 256, 0, stream>>>(W, WpackS);

    // 2) zero counts, then fused (striped) GEMM + histogram + cv pack
    hipMemsetAsync(counts, 0, (size_t)N_NODES * sizeof(int), stream);
    gemm_hist_cv<<<FUSED_NB, 256, 0, stream>>>(
        x, (const bf16x8*)WpackS, support, erow, ecol, eval, counts, cv);

    // 3) hierarchical scan -> offsets, cursor
    partial_k<<<SCAN_NB, 256, 0, stream>>>(counts, bsum);
    scan_bsum_k<<<1, 128, 0, stream>>>(bsum, bpre, offsets);
    emit_k<<<SCAN_NB, 256, 0, stream>>>(counts, bpre, offsets, cursor);

    // 4) predicated CSR fill, 2 L2-localized passes
    for (int p = 0; p < FILL_PASSES; ++p) {
        fill_k<<<FILL_NB, 256, 0, stream>>>(erow, cv, cursor, csr,
                                            p * PASS_NODES, (p + 1) * PASS_NODES);
    }

    // 5) aggregate + ReLU (no atomics, writes every output element)
    agg_k<<<(N_NODES + 3) / 4, 256, 0, stream>>>(offsets, csr, support, out);
}